// Round 11
// baseline (28.804 us; speedup 1.0000x reference)
//
#include <hip/hip_runtime.h>
#include <math.h>

#define KLEN 512
#define QLEN 64
#define ADIM 512
#define BATCH 4
#define NH 4

typedef __attribute__((ext_vector_type(8))) short bf16x8;
typedef __attribute__((ext_vector_type(4))) float f32x4;
typedef _Float16 f16;
typedef __attribute__((ext_vector_type(2))) _Float16 f16x2;

__device__ __forceinline__ f16x2 u2h(unsigned int u) {
  union { unsigned int u; f16x2 h; } v; v.u = u; return v.h;
}

// Pack float4 -> 4 bf16 (short4) by truncation (RTZ): one v_perm_b32 per pair.
__device__ __forceinline__ short4 pack4(float4 x) {
  union { unsigned int u[2]; short4 s; } o;
  o.u[0] = __builtin_amdgcn_perm(__float_as_uint(x.y), __float_as_uint(x.x), 0x07060302);
  o.u[1] = __builtin_amdgcn_perm(__float_as_uint(x.w), __float_as_uint(x.z), 0x07060302);
  return o.s;
}

// ---------------------------------------------------------------------------
// proj_mfma — BYTE-IDENTICAL to round 10 (measurement control).
// ---------------------------------------------------------------------------
__global__ __launch_bounds__(512) void proj_mfma(
    const float* __restrict__ key, const float* __restrict__ query,
    const float* __restrict__ wk, const float* __restrict__ bk,
    const float* __restrict__ wq,
    const float* __restrict__ v_v, const float* __restrict__ v_g,
    f16* __restrict__ Kp, f16* __restrict__ Qp, f16* __restrict__ Wn) {
  __shared__ short At[2][64 * 40];
  __shared__ short Wt[2][64 * 40];

  const int bid = blockIdx.x;
  const int tid = threadIdx.x;

  if (bid == 288) {  // ---- wnorm (512 threads: 1 elem each) ----
    __shared__ float wred[512];
    for (int h = 0; h < NH; ++h) {
      float v0 = v_v[h * ADIM + tid];
      wred[tid] = v0 * v0;
      __syncthreads();
      for (int s2 = 256; s2 > 0; s2 >>= 1) {
        if (tid < s2) wred[tid] += wred[tid + s2];
        __syncthreads();
      }
      float scale = v_g[h] / sqrtf(wred[0]);
      Wn[h * ADIM + tid] = (f16)(v0 * scale);
      __syncthreads();
    }
    return;
  }

  const float *A, *W, *bias;
  f16* C;
  int m0, a0;
  if (bid < 256) {
    A = key; W = wk; bias = bk; C = Kp;
    m0 = (bid >> 3) * 64; a0 = (bid & 7) * 64;
  } else {
    const int t = bid - 256;
    A = query; W = wq; bias = nullptr; C = Qp;
    m0 = (t >> 3) * 64; a0 = (t & 7) * 64;
  }

  const int w = tid >> 6;
  const int wr = w >> 2;          // 0..1 (32 m-rows each)
  const int wc = w & 3;           // 0..3 (16 n-cols each)
  const int lane = tid & 63;
  const int lr = lane & 15, hi = lane >> 4;
  const int srow = tid >> 3;      // staging row 0..63
  const int scol = (tid & 7) * 4; // staging f32 col 0..28

  const float* Arow = &A[(size_t)(m0 + srow) * ADIM + scol];
  const float* Wrow = &W[(size_t)(a0 + srow) * ADIM + scol];

  f32x4 acc0 = {0.f, 0.f, 0.f, 0.f};
  f32x4 acc1 = {0.f, 0.f, 0.f, 0.f};

  {  // prologue: chunk 0 -> buf 0
    float4 fa = *(const float4*)&Arow[0];
    float4 fw = *(const float4*)&Wrow[0];
    *(short4*)&At[0][srow * 40 + scol] = pack4(fa);
    *(short4*)&Wt[0][srow * 40 + scol] = pack4(fw);
  }
  __syncthreads();

  for (int c = 0; c < 16; ++c) {
    float4 na, nw;
    if (c < 15) {
      na = *(const float4*)&Arow[(c + 1) * 32];
      nw = *(const float4*)&Wrow[(c + 1) * 32];
    }
    const short* Ab = At[c & 1];
    const short* Wb = Wt[c & 1];
    bf16x8 af0 = *(const bf16x8*)&Ab[(wr * 32 + lr) * 40 + hi * 8];
    bf16x8 af1 = *(const bf16x8*)&Ab[(wr * 32 + 16 + lr) * 40 + hi * 8];
    bf16x8 wf  = *(const bf16x8*)&Wb[(wc * 16 + lr) * 40 + hi * 8];
    acc0 = __builtin_amdgcn_mfma_f32_16x16x32_bf16(af0, wf, acc0, 0, 0, 0);
    acc1 = __builtin_amdgcn_mfma_f32_16x16x32_bf16(af1, wf, acc1, 0, 0, 0);
    if (c < 15) {
      *(short4*)&At[(c + 1) & 1][srow * 40 + scol] = pack4(na);
      *(short4*)&Wt[(c + 1) & 1][srow * 40 + scol] = pack4(nw);
    }
    __syncthreads();
  }

  const int ccol = a0 + wc * 16 + lr;
  const float bv = bias ? bias[ccol] : 0.f;
#pragma unroll
  for (int i = 0; i < 4; ++i) {
    const int crow0 = m0 + wr * 32 + hi * 4 + i;
    C[(size_t)crow0 * ADIM + ccol] = (f16)(acc0[i] + bv);
    C[(size_t)(crow0 + 16) * ADIM + ccol] = (f16)(acc1[i] + bv);
  }
}

// ---------------------------------------------------------------------------
// energy v11: e[b,n,q,kl] = sum_a relu(Kp+Qp)*Wn + r ; masked -> 0xFF7F0000.
// DELTAS vs r10 (proj unchanged -> Δtotal = Δenergy):
//  - grid (64,4,4) = 1024 blocks, tile 8kl x 16q -> 4 blocks/CU, 4 waves/SIMD
//  - per-thread acc 16 -> 8 f32 (1 kl x 2 q x 4 n)
//  - s-loop `#pragma unroll 2`: caps LDS-read hoisting (spill guard)
// ---------------------------------------------------------------------------
__global__ __launch_bounds__(256) void energy_kernel(
    const f16* __restrict__ Kp, const f16* __restrict__ Qp,
    const f16* __restrict__ Wn, const int* __restrict__ mask,
    const float* __restrict__ r, float* __restrict__ out) {
  __shared__ f16 Kl[8 * 520];
  __shared__ f16 Ql[16 * 520];
  __shared__ float Red[2][640];  // [wavepair][cell*5 + n], cell = q*8+kl

  const int b = blockIdx.z;
  const int q0 = blockIdx.y * 16;
  const int kl0 = blockIdx.x * 8;
  const int tid = threadIdx.x;
  const int wave = tid >> 6;
  const int lane = tid & 63;
  const int klg = lane & 7;    // 0..7: this thread's kl row
  const int qg = lane >> 3;    // 0..7: q and q+8

  const float rv = r[0];

  const unsigned short* Kb = (const unsigned short*)(Kp + ((size_t)b * KLEN + kl0) * ADIM);
  const unsigned short* Qb = (const unsigned short*)(Qp + ((size_t)b * QLEN + q0) * ADIM);

  // W slice for this wave's a-range into regs: lane n*16+s holds
  // Wd[n*256 + wave*64 + s*4 .. +4]  (uint4 = 8 f16 = the 8 a of step s)
  const unsigned int* Wd = (const unsigned int*)Wn;  // [4][256] dwords
  uint4 wreg = *(const uint4*)&Wd[(lane >> 4) * 256 + wave * 64 + (lane & 15) * 4];

  // stage K: 8x512 halves = 512 uint4 -> 2/thread; Q: 16x512 = 1024 -> 4/thread
#pragma unroll
  for (int j = 0; j < 2; ++j) {
    const int u = tid + 256 * j;
    const int row = u >> 6, c8 = (u & 63) * 8;
    *(uint4*)&Kl[row * 520 + c8] = *(const uint4*)&Kb[row * ADIM + c8];
  }
#pragma unroll
  for (int j = 0; j < 4; ++j) {
    const int u = tid + 256 * j;
    const int row = u >> 6, c8 = (u & 63) * 8;
    *(uint4*)&Ql[row * 520 + c8] = *(const uint4*)&Qb[row * ADIM + c8];
  }
  __syncthreads();

  float acc[2][4] = {};  // [q-half][n]
  const int abase = wave * 128;

#pragma unroll 2
  for (int s = 0; s < 16; ++s) {
    const int off = abase + s * 8;
    uint4 ka = *(const uint4*)&Kl[klg * 520 + off];
    uint4 qa = *(const uint4*)&Ql[qg * 520 + off];
    uint4 qb = *(const uint4*)&Ql[(qg + 8) * 520 + off];
    unsigned wdw[4][4];
#pragma unroll
    for (int n = 0; n < 4; ++n) {
      wdw[n][0] = (unsigned)__builtin_amdgcn_readlane((int)wreg.x, n * 16 + s);
      wdw[n][1] = (unsigned)__builtin_amdgcn_readlane((int)wreg.y, n * 16 + s);
      wdw[n][2] = (unsigned)__builtin_amdgcn_readlane((int)wreg.z, n * 16 + s);
      wdw[n][3] = (unsigned)__builtin_amdgcn_readlane((int)wreg.w, n * 16 + s);
    }
    unsigned ks[4] = {ka.x, ka.y, ka.z, ka.w};
    unsigned qs[2][4] = {{qa.x, qa.y, qa.z, qa.w}, {qb.x, qb.y, qb.z, qb.w}};
#pragma unroll
    for (int j = 0; j < 4; ++j) {
      const f16x2 wv0 = u2h(wdw[0][j]), wv1 = u2h(wdw[1][j]);
      const f16x2 wv2 = u2h(wdw[2][j]), wv3 = u2h(wdw[3][j]);
      const f16x2 kv = u2h(ks[j]);
#pragma unroll
      for (int qi = 0; qi < 2; ++qi) {
        f16x2 sum = kv + u2h(qs[qi][j]);
        f16x2 rl = __builtin_elementwise_max(sum, (f16x2)(_Float16)0);
        acc[qi][0] = __builtin_amdgcn_fdot2(rl, wv0, acc[qi][0], false);
        acc[qi][1] = __builtin_amdgcn_fdot2(rl, wv1, acc[qi][1], false);
        acc[qi][2] = __builtin_amdgcn_fdot2(rl, wv2, acc[qi][2], false);
        acc[qi][3] = __builtin_amdgcn_fdot2(rl, wv3, acc[qi][3], false);
      }
    }
  }

  // ---- cross-wave reduction: waves 0/1 store, waves 2/3 add ----
  const int half = wave & 1;
  if (wave < 2) {
#pragma unroll
    for (int qi = 0; qi < 2; ++qi) {
      const int cell = (qg + 8 * qi) * 8 + klg;
#pragma unroll
      for (int n = 0; n < 4; ++n) Red[half][cell * 5 + n] = acc[qi][n];
    }
  }
  __syncthreads();
  if (wave >= 2) {
#pragma unroll
    for (int qi = 0; qi < 2; ++qi) {
      const int cell = (qg + 8 * qi) * 8 + klg;
#pragma unroll
      for (int n = 0; n < 4; ++n) Red[half][cell * 5 + n] += acc[qi][n];
    }
  }
  __syncthreads();

  // epilogue: 512 outputs [n][q][klp], 2 per thread (float2 store)
  const float NEG_BIG = __uint_as_float(0xFF7F0000u);  // finite under bf16 cast
  const int j0 = tid * 2;
  const int n = j0 >> 7;
  const int q = (j0 >> 3) & 15;
  const int klp = j0 & 7;
  const int2 mv = *(const int2*)&mask[((size_t)b * QLEN + q0 + q) * KLEN + kl0 + klp];
  float2 o;
  {
    const int c0 = q * 8 + klp, c1 = q * 8 + klp + 1;
    float v0 = Red[0][c0 * 5 + n] + Red[1][c0 * 5 + n] + rv;
    float v1 = Red[0][c1 * 5 + n] + Red[1][c1 * 5 + n] + rv;
    o.x = mv.x ? v0 : NEG_BIG;
    o.y = mv.y ? v1 : NEG_BIG;
  }
  *(float2*)&out[(((size_t)b * NH + n) * QLEN + q0 + q) * KLEN + kl0 + klp] = o;
}

extern "C" void kernel_launch(void* const* d_in, const int* in_sizes, int n_in,
                              void* d_out, int out_size, void* d_ws, size_t ws_size,
                              hipStream_t stream) {
  const float* key   = (const float*)d_in[0];  // [4,512,512] f32
  const float* query = (const float*)d_in[1];  // [4,64,512]  f32
  const int*   mask  = (const int*)d_in[2];    // [4,64,512]  i32
  const float* wk    = (const float*)d_in[3];  // [512,512]   f32
  const float* bk    = (const float*)d_in[4];  // [512]       f32
  const float* wq    = (const float*)d_in[5];  // [512,512]   f32
  const float* v_v   = (const float*)d_in[6];  // [4,512]     f32
  const float* v_g   = (const float*)d_in[7];  // [4,1]       f32
  const float* r     = (const float*)d_in[8];  // [1]         f32
  float* out = (float*)d_out;                  // [4,4,64,512] f32

  f16* Kp = (f16*)d_ws;                        // 2048*512 f16 = 2 MiB
  f16* Qp = Kp + (size_t)2048 * 512;           // 256*512  f16 = 256 KiB
  f16* Wn = Qp + (size_t)256 * 512;            // 4*512    f16 = 4 KiB

  hipLaunchKernelGGL(proj_mfma, dim3(289), dim3(512), 0, stream,
                     key, query, wk, bk, wq, v_v, v_g, Kp, Qp, Wn);
  hipLaunchKernelGGL(energy_kernel, dim3(64, 4, 4), dim3(256), 0, stream,
                     Kp, Qp, Wn, mask, r, out);
}